// Round 6
// baseline (35256.857 us; speedup 1.0000x reference)
//
#include <hip/hip_runtime.h>

typedef unsigned short u16;
typedef unsigned int   u32;
typedef unsigned char  u8;

constexpr int kB = 32, kT = 128, kS = 256, kE = 512, kH = 1024, kG = 4096;

__device__ __forceinline__ float b2f(u16 v){ return __uint_as_float(((u32)v) << 16); }
__device__ __forceinline__ float sigf(float x){ return 1.f / (1.f + expf(-x)); }
// dt==0: buffer is bf16 (u16); dt==1: buffer is fp32
__device__ __forceinline__ float ldin(const void* p, size_t i, int dt){
    return dt ? ((const float*)p)[i] : b2f(((const u16*)p)[i]);
}

// ---------------- input dtype detection (bf16 vs fp32) ----------------
__global__ void detect_dtype_k(const void* __restrict__ inputs, int* __restrict__ dtflag)
{
    __shared__ int bad;
    int t = threadIdx.x;
    if (t == 0) bad = 0;
    __syncthreads();
    const u16* p = (const u16*)inputs;
    int l = 0;
    for (int i = t; i < 4096; i += 256){
        u16 v = p[i];
        int e = (v >> 7) & 0xFF;
        if (v != 0 && (e < 90 || e > 140)) l = 1;
    }
    if (l) atomicOr(&bad, 1);
    __syncthreads();
    if (t == 0) *dtflag = bad;   // 1 = fp32, 0 = bf16
}

// ---------------- mask detection -> maskflag[b][s] = 1.0 (pad) / 0.0 ----------------
__global__ void prep_mask_k(const void* __restrict__ mask, float* __restrict__ maskflag)
{
    __shared__ int bad32, bad16, bad8, evenNZ;
    int t = threadIdx.x;
    if (t == 0){ bad32 = 0; bad16 = 0; bad8 = 0; evenNZ = 0; }
    __syncthreads();
    const u32* w32 = (const u32*)mask;
    const u16* w16 = (const u16*)mask;
    const u8*  w8  = (const u8*)mask;
    int l32 = 0, l16 = 0, l8 = 0, lev = 0;
    for (int i = t; i < 2048; i += 256){ u32 v = w32[i]; l32 |= (v > 1u); }
    for (int i = t; i < 4096; i += 256){
        u16 v = w16[i];
        l16 |= (v != 0 && v != 0x3F80u);
        if ((i & 1) == 0 && v != 0) lev = 1;
    }
    for (int i = t; i < 8192; i += 256){ l8 |= (w8[i] > 1); }
    if (l32) atomicOr(&bad32, 1);
    if (l16) atomicOr(&bad16, 1);
    if (l8)  atomicOr(&bad8, 1);
    if (lev) atomicOr(&evenNZ, 1);
    __syncthreads();
    int mode;                       // 0=int32, 1=bf16, 2=uint8, 3=fp32
    if (!bad32)       mode = 0;
    else if (!bad16)  mode = evenNZ ? 1 : 3;
    else if (!bad8)   mode = 2;
    else              mode = 3;
    for (int i = t; i < kB * kS; i += 256){
        bool m;
        if (mode == 0)      m = (((const int*)mask)[i] != 0);
        else if (mode == 1) m = (w16[i] != 0);
        else if (mode == 2) m = (w8[i] != 0);
        else                m = (((const float*)mask)[i] != 0.f);
        maskflag[i] = m ? 1.f : 0.f;
    }
}

// ---------------- bias copies to fp32 (no algebra except bih+bhh) ----------------
__global__ void copy_bias_k(const void* __restrict__ bq, const void* __restrict__ bk,
                            const void* __restrict__ bv, const void* __restrict__ bo,
                            const void* __restrict__ bih0, const void* __restrict__ bhh0,
                            const void* __restrict__ bih1, const void* __restrict__ bhh1,
                            float* __restrict__ bqf, float* __restrict__ bkf,
                            float* __restrict__ bvf, float* __restrict__ bof,
                            float* __restrict__ bias01, float* __restrict__ bias1,
                            const int* __restrict__ dtflag)
{
    int dt = *dtflag;
    int idx = blockIdx.x * 256 + threadIdx.x;   // grid 48 -> 12288
    if (idx < 1024)       bqf[idx]        = ldin(bq, idx, dt);
    else if (idx < 2048)  bkf[idx - 1024] = ldin(bk, idx - 1024, dt);
    else if (idx < 3072)  bvf[idx - 2048] = ldin(bv, idx - 2048, dt);
    else if (idx < 4096)  bof[idx - 3072] = ldin(bo, idx - 3072, dt);
    else if (idx < 8192){ int j = idx - 4096; bias01[j] = ldin(bih0, j, dt) + ldin(bhh0, j, dt); }
    else               { int j = idx - 8192; bias1[j]  = ldin(bih1, j, dt) + ldin(bhh1, j, dt); }
}

// ---------------- inputs -> fp32 copy, same [B,T,E] layout ----------------
__global__ void copy_inputs_k(const void* __restrict__ inputs, float* __restrict__ xf,
                              const int* __restrict__ dtflag)
{
    int dt = *dtflag;
    int idx = blockIdx.x * 256 + threadIdx.x;   // grid 8192 -> 2097152
    xf[idx] = ldin(inputs, idx, dt);
}

// ---------------- initial states: c = concat(enc_c[0], enc_c[1]) both layers, h = 0 ----------------
__global__ void init_state_k(const void* __restrict__ enc_c, float* __restrict__ h0,
                             float* __restrict__ c0, float* __restrict__ h1,
                             float* __restrict__ c1, const int* __restrict__ dtflag)
{
    int dt = *dtflag;
    int idx = blockIdx.x * 256 + threadIdx.x;     // 32768
    int b = idx >> 10, h = idx & 1023;
    float cv = (h < 512) ? ldin(enc_c, (size_t)b * 512 + h, dt)
                         : ldin(enc_c, (size_t)(32 + b) * 512 + (h - 512), dt);
    h0[idx] = 0.f; h1[idx] = 0.f; c0[idx] = cv; c1[idx] = cv;
}

// ---------------- transpose: WT[e*ldt + j] = W[j*ldw + col_off + e] ----------------
// grid (jmax/64, emax/64), block 256
__global__ void transpose_k(const void* __restrict__ W, int ldw, int col_off,
                            float* __restrict__ WT, int ldt, const int* __restrict__ dtflag)
{
    __shared__ float tile[64][65];
    int dt = *dtflag;
    int j0 = blockIdx.x * 64, e0 = blockIdx.y * 64;
    for (int i = 0; i < 16; i++){
        int idx = threadIdx.x + i * 256;
        int jr = idx >> 6, ec = idx & 63;
        tile[jr][ec] = ldin(W, (size_t)(j0 + jr) * ldw + col_off + e0 + ec, dt);
    }
    __syncthreads();
    for (int i = 0; i < 16; i++){
        int idx = threadIdx.x + i * 256;
        int er = idx >> 6, jc = idx & 63;
        WT[(size_t)(e0 + er) * ldt + j0 + jc] = tile[jc][er];
    }
}

// ---------------- K/V projection GEMM (literal: out[r][c] = sum_k A[r][k]*B[c][k] + bias[c]) ----------------
// A = enc rows r=s*32+b (raw input, dt), B = Wk/Wv c-major rows (raw, dt), out fp32 [r][c]
__global__ __launch_bounds__(256) void gemm_kv_k(
    const void* __restrict__ A, const void* __restrict__ Bm,
    float* __restrict__ Out, const float* __restrict__ bias,
    const int* __restrict__ dtflag)
{
    __shared__ float As[32][68];
    __shared__ float Bs[32][68];
    const int dt = *dtflag;
    const int tid = threadIdx.x;
    const int tile_r = blockIdx.x * 64, tile_c = blockIdx.y * 64;
    const int r0 = (tid & 15) * 4, c0 = (tid >> 4) * 4;
    float acc[16];
    #pragma unroll
    for (int i = 0; i < 16; i++) acc[i] = 0.f;

    for (int k0 = 0; k0 < 1024; k0 += 32){
        int rr = tid & 63, kq = tid >> 6;
        #pragma unroll
        for (int i = 0; i < 8; i++){
            int k = kq * 8 + i;
            As[k][rr] = ldin(A, (size_t)(tile_r + rr) * 1024 + k0 + k, dt);
        }
        #pragma unroll
        for (int i = 0; i < 8; i++){
            int k = kq * 8 + i;
            Bs[k][rr] = ldin(Bm, (size_t)(tile_c + rr) * 1024 + k0 + k, dt);
        }
        __syncthreads();
        #pragma unroll
        for (int k = 0; k < 32; k++){
            float4 av = *(const float4*)&As[k][r0];
            float4 bv = *(const float4*)&Bs[k][c0];
            acc[0]  += av.x * bv.x; acc[1]  += av.x * bv.y; acc[2]  += av.x * bv.z; acc[3]  += av.x * bv.w;
            acc[4]  += av.y * bv.x; acc[5]  += av.y * bv.y; acc[6]  += av.y * bv.z; acc[7]  += av.y * bv.w;
            acc[8]  += av.z * bv.x; acc[9]  += av.z * bv.y; acc[10] += av.z * bv.z; acc[11] += av.z * bv.w;
            acc[12] += av.w * bv.x; acc[13] += av.w * bv.y; acc[14] += av.w * bv.z; acc[15] += av.w * bv.w;
        }
        __syncthreads();
    }
    #pragma unroll
    for (int i = 0; i < 4; i++){
        int gr = tile_r + r0 + i;
        #pragma unroll
        for (int jj = 0; jj < 4; jj++){
            int gc = tile_c + c0 + jj;
            Out[(size_t)gr * 1024 + gc] = acc[i * 4 + jj] + bias[gc];
        }
    }
}

// ---------------- generic split-K small-M GEMM partial ----------------
// partial[(sl_off+es)*32 + b][j (of N)] = sum_{k in slice es (128 wide)} WT[k*N+j] * act[b*bstride + k]
// grid (N/256, K/128)
__global__ __launch_bounds__(256) void splitk_k(
    const float* __restrict__ WT, const float* __restrict__ act, int bstride,
    float* __restrict__ partial, int N, int sl_off)
{
    int j = blockIdx.x * 256 + threadIdx.x;
    int es = blockIdx.y;
    int e0 = es * 128;
    float acc[32];
    #pragma unroll
    for (int b = 0; b < 32; b++) acc[b] = 0.f;
    #pragma unroll
    for (int ec = 0; ec < 2; ec++){
        float w[64];
        const float* wp = WT + (size_t)(e0 + ec * 64) * N + j;
        #pragma unroll
        for (int k = 0; k < 64; k++) w[k] = wp[(size_t)k * N];
        const float* ap = act + e0 + ec * 64;
        #pragma unroll 4
        for (int b = 0; b < 32; b++){
            const float* ab = ap + (size_t)b * bstride;
            float s0 = 0.f, s1 = 0.f;
            #pragma unroll
            for (int k = 0; k < 64; k += 2){ s0 += w[k] * ab[k]; s1 += w[k + 1] * ab[k + 1]; }
            acc[b] += s0 + s1;
        }
    }
    float* po = partial + (size_t)((sl_off + es) * 32) * N + j;
    #pragma unroll 4
    for (int b = 0; b < 32; b++) po[(size_t)b * N] = acc[b];
}

// ---------------- reduce N=1024 partials + bias -> out[b][n] ----------------
__global__ __launch_bounds__(256) void reduce1024_k(
    const float* __restrict__ partial, int nsl, const float* __restrict__ bias,
    float* __restrict__ out)
{
    int idx = blockIdx.x * 256 + threadIdx.x;   // grid 128 -> 32768
    int b = idx >> 10, n = idx & 1023;
    float s = bias[n];
    for (int es = 0; es < nsl; es++) s += partial[(size_t)(es * 32 + b) * 1024 + n];
    out[idx] = s;
}

// ---------------- scores[b][s] = mask ? -1e9 : (sum_h q[b,h]*K[s,b,h]) * scale ----------------
__global__ __launch_bounds__(256) void scores_k(
    const float* __restrict__ q, const float* __restrict__ K,
    const float* __restrict__ maskflag, float* __restrict__ scores)
{
    int w = (blockIdx.x * 256 + threadIdx.x) >> 6;    // 0..8191
    int lane = threadIdx.x & 63;
    int b = w >> 8, s = w & 255;
    const float* kr = K + ((size_t)(s * 32 + b) << 10) + lane * 16;
    const float* qr = q + ((size_t)b << 10) + lane * 16;
    float acc = 0.f;
    #pragma unroll
    for (int i = 0; i < 16; i++) acc += qr[i] * kr[i];
    #pragma unroll
    for (int off = 32; off; off >>= 1) acc += __shfl_down(acc, off, 64);
    if (lane == 0){
        int idx = b * kS + s;
        scores[idx] = (maskflag[idx] != 0.f) ? -1e9f : acc * 0.03125f;
    }
}

// ---------------- softmax over s + cv[b][h] = sum_s attn[b,s]*V[s,b,h] ----------------
__global__ __launch_bounds__(256) void softmax_cv_k(
    const float* __restrict__ scores, const float* __restrict__ V,
    float* __restrict__ cv)
{
    __shared__ float attn[256];
    __shared__ float wred[8];
    int b = blockIdx.x >> 2, ht = blockIdx.x & 3;
    int tid = threadIdx.x;
    float sc = scores[b * kS + tid];
    float m = sc;
    #pragma unroll
    for (int off = 32; off; off >>= 1) m = fmaxf(m, __shfl_down(m, off, 64));
    if ((tid & 63) == 0) wred[tid >> 6] = m;
    __syncthreads();
    float mm = fmaxf(fmaxf(wred[0], wred[1]), fmaxf(wred[2], wred[3]));
    float ex = expf(sc - mm);
    float ssum = ex;
    #pragma unroll
    for (int off = 32; off; off >>= 1) ssum += __shfl_down(ssum, off, 64);
    if ((tid & 63) == 0) wred[4 + (tid >> 6)] = ssum;
    __syncthreads();
    float tot = (wred[4] + wred[5]) + (wred[6] + wred[7]);
    attn[tid] = ex / tot;
    __syncthreads();
    int h = ht * 256 + tid;
    const float* vcol = V + ((size_t)b << 10) + h;   // V[(s*32+b)*1024 + h], s-stride 32768
    float acc = 0.f;
    #pragma unroll 8
    for (int s = 0; s < kS; s++) acc += attn[s] * vcol[(size_t)s << 15];
    cv[(b << 10) + h] = acc;
}

// ---------------- LSTM cell: g = sum partials + bias; update c,h; optional FP32 y ----------------
// OUTPUT IS FP32: reference returns jnp.float32, harness allocates d_out as float*.
// (r2/r3/r5 wrote bf16 here -> checker's fp32 view gave the frozen 0.9590 absmax.)
__global__ __launch_bounds__(256) void lstm_cell_k(
    const float* __restrict__ partial, int nsl, const float* __restrict__ biasv,
    const float* __restrict__ c_prev, float* __restrict__ c_out, float* __restrict__ h_out,
    float* __restrict__ y_out, int t)
{
    int idx = blockIdx.x * 256 + threadIdx.x;     // 32768
    int b = idx >> 10, h = idx & 1023;
    float g[4];
    #pragma unroll
    for (int gi = 0; gi < 4; gi++){
        int j = gi * 1024 + h;
        float s = biasv[j];
        for (int es = 0; es < nsl; es++) s += partial[(size_t)(es * 32 + b) * kG + j];
        g[gi] = s;
    }
    float gi_ = sigf(g[0]);
    float gf_ = sigf(g[1]);
    float gg_ = tanhf(g[2]);
    float go_ = sigf(g[3]);
    float c = gf_ * c_prev[idx] + gi_ * gg_;
    float hh = go_ * tanhf(c);
    c_out[idx] = c;
    h_out[idx] = hh;
    if (y_out) y_out[((size_t)b * kT + t) * kH + h] = hh;
}

extern "C" void kernel_launch(void* const* d_in, const int* in_sizes, int n_in,
                              void* d_out, int out_size, void* d_ws, size_t ws_size,
                              hipStream_t stream)
{
    const void* inputs = d_in[0];
    const void* enc    = d_in[1];
    const void* enc_c  = d_in[2];
    const void* mask   = d_in[3];
    const void* Wq   = d_in[4];
    const void* bq   = d_in[5];
    const void* Wk   = d_in[6];
    const void* bk   = d_in[7];
    const void* Wv   = d_in[8];
    const void* bv   = d_in[9];
    const void* Wo   = d_in[10];
    const void* bo   = d_in[11];
    const void* Wih0 = d_in[12];
    const void* Whh0 = d_in[13];
    const void* bih0 = d_in[14];
    const void* bhh0 = d_in[15];
    const void* Wih1 = d_in[16];
    const void* Whh1 = d_in[17];
    const void* bih1 = d_in[18];
    const void* bhh1 = d_in[19];
    float* out = (float*)d_out;
    (void)in_sizes; (void)n_in; (void)out_size; (void)ws_size;

    char* ws = (char*)d_ws;
    size_t off = 0;
    auto alloc = [&](size_t bytes) -> void* {
        void* p = ws + off; off += (bytes + 255) & ~(size_t)255; return p;
    };
    float* xf     = (float*)alloc((size_t)kB * kT * kE * 4);          // 8.4 MB [b][t][e]
    float* K      = (float*)alloc((size_t)kS * kB * kH * 4);          // 33.6 MB [s][b][h]
    float* V      = (float*)alloc((size_t)kS * kB * kH * 4);          // 33.6 MB [s][b][h]
    float* WqT    = (float*)alloc((size_t)kH * kH * 4);               // WqT[o][i] = Wq[i][o]
    float* WoT    = (float*)alloc((size_t)kH * kH * 4);               // WoT[h][o2] = Wo[o2][h]
    float* WTx    = (float*)alloc((size_t)kE * kG * 4);               // Wih0[:,1024:]^T
    float* WTc    = (float*)alloc((size_t)kH * kG * 4);               // Wih0[:,0:1024]^T
    float* WThh0  = (float*)alloc((size_t)kH * kG * 4);
    float* WTih1  = (float*)alloc((size_t)kH * kG * 4);
    float* WThh1  = (float*)alloc((size_t)kH * kG * 4);
    float* partial= (float*)alloc(((size_t)20 * 32 * kG + (size_t)8 * 32 * kH) * 4);
    float* qpart  = partial + (size_t)20 * 32 * kG;                   // aliased tail, 8 slices N=1024
    float* bqf    = (float*)alloc(1024 * 4);
    float* bkf    = (float*)alloc(1024 * 4);
    float* bvf    = (float*)alloc(1024 * 4);
    float* bof    = (float*)alloc(1024 * 4);
    float* bias01 = (float*)alloc(4096 * 4);
    float* bias1  = (float*)alloc(4096 * 4);
    float* maskflag=(float*)alloc(kB * kS * 4);
    float* scores = (float*)alloc(kB * kS * 4);
    float* qbuf   = (float*)alloc(kB * kH * 4);
    float* cv     = (float*)alloc(kB * kH * 4);
    float* ctx    = (float*)alloc(kB * kH * 4);
    float* h0f    = (float*)alloc(kB * kH * 4);
    float* c0f    = (float*)alloc(kB * kH * 4);
    float* h1f    = (float*)alloc(kB * kH * 4);
    float* c1f    = (float*)alloc(kB * kH * 4);
    int*   dtflag = (int*)alloc(256);

    // ---- one-time precompute (literal; only hoists what the reference hoists) ----
    detect_dtype_k<<<1, 256, 0, stream>>>(inputs, dtflag);
    prep_mask_k<<<1, 256, 0, stream>>>(mask, maskflag);
    copy_bias_k<<<48, 256, 0, stream>>>(bq, bk, bv, bo, bih0, bhh0, bih1, bhh1,
                                        bqf, bkf, bvf, bof, bias01, bias1, dtflag);
    copy_inputs_k<<<8192, 256, 0, stream>>>(inputs, xf, dtflag);
    init_state_k<<<128, 256, 0, stream>>>(enc_c, h0f, c0f, h1f, c1f, dtflag);
    transpose_k<<<dim3(16, 16), 256, 0, stream>>>(Wq,   1024, 0,    WqT,   1024, dtflag);
    transpose_k<<<dim3(16, 16), 256, 0, stream>>>(Wo,   1024, 0,    WoT,   1024, dtflag);
    transpose_k<<<dim3(64, 8),  256, 0, stream>>>(Wih0, 1536, 1024, WTx,   4096, dtflag);
    transpose_k<<<dim3(64, 16), 256, 0, stream>>>(Wih0, 1536, 0,    WTc,   4096, dtflag);
    transpose_k<<<dim3(64, 16), 256, 0, stream>>>(Whh0, 1024, 0,    WThh0, 4096, dtflag);
    transpose_k<<<dim3(64, 16), 256, 0, stream>>>(Wih1, 1024, 0,    WTih1, 4096, dtflag);
    transpose_k<<<dim3(64, 16), 256, 0, stream>>>(Whh1, 1024, 0,    WThh1, 4096, dtflag);
    // K[s,b,h] = sum_e enc[s,b,e]*Wk[h,e] + bk[h] ; V likewise
    gemm_kv_k<<<dim3(128, 16), 256, 0, stream>>>(enc, Wk, K, bkf, dtflag);
    gemm_kv_k<<<dim3(128, 16), 256, 0, stream>>>(enc, Wv, V, bvf, dtflag);

    // ---- recurrent loop: literal reference step ----
    for (int t = 0; t < kT; t++){
        // q = c1 @ Wq.T + bq
        splitk_k<<<dim3(4, 8), 256, 0, stream>>>(WqT, c1f, 1024, qpart, 1024, 0);
        reduce1024_k<<<128, 256, 0, stream>>>(qpart, 8, bqf, qbuf);
        // scores = where(mask, -1e9, (q . K) * scale)
        scores_k<<<2048, 256, 0, stream>>>(qbuf, K, maskflag, scores);
        // attn = softmax(scores); cv = attn @ V
        softmax_cv_k<<<128, 256, 0, stream>>>(scores, V, cv);
        // ctx = cv @ Wo.T + bo
        splitk_k<<<dim3(4, 8), 256, 0, stream>>>(WoT, cv, 1024, qpart, 1024, 0);
        reduce1024_k<<<128, 256, 0, stream>>>(qpart, 8, bof, ctx);
        // layer 0: g = [ctx,x_t] @ Wih0.T + h0 @ Whh0.T + (bih0+bhh0)
        splitk_k<<<dim3(16, 4), 256, 0, stream>>>(WTx, xf + (size_t)t * kE, kT * kE, partial, 4096, 0);
        splitk_k<<<dim3(16, 8), 256, 0, stream>>>(WTc, ctx, 1024, partial, 4096, 4);
        splitk_k<<<dim3(16, 8), 256, 0, stream>>>(WThh0, h0f, 1024, partial, 4096, 12);
        lstm_cell_k<<<128, 256, 0, stream>>>(partial, 20, bias01, c0f, c0f, h0f, nullptr, t);
        // layer 1: g = h0 @ Wih1.T + h1 @ Whh1.T + (bih1+bhh1)
        splitk_k<<<dim3(16, 8), 256, 0, stream>>>(WTih1, h0f, 1024, partial, 4096, 0);
        splitk_k<<<dim3(16, 8), 256, 0, stream>>>(WThh1, h1f, 1024, partial, 4096, 8);
        lstm_cell_k<<<128, 256, 0, stream>>>(partial, 16, bias1, c1f, c1f, h1f, out, t);
    }
}

// Round 7
// 15747.476 us; speedup vs baseline: 2.2389x; 2.2389x over previous
//
#include <hip/hip_runtime.h>

typedef unsigned short u16;
typedef unsigned int   u32;
typedef unsigned char  u8;

constexpr int kB = 32, kT = 128, kS = 256, kE = 512, kH = 1024, kG = 4096;

__device__ __forceinline__ float b2f(u16 v){ return __uint_as_float(((u32)v) << 16); }
__device__ __forceinline__ u16  f2b(float f){
    u32 u = __float_as_uint(f);
    return (u16)((u + 0x7FFFu + ((u >> 16) & 1u)) >> 16);
}
__device__ __forceinline__ float sigf(float x){ return 1.f / (1.f + expf(-x)); }
// dt==0: buffer is bf16 (u16); dt==1: buffer is fp32 (validated: fp32 on this harness)
__device__ __forceinline__ float ldin(const void* p, size_t i, int dt){
    return dt ? ((const float*)p)[i] : b2f(((const u16*)p)[i]);
}

// ---------------- input dtype detection (bf16 vs fp32) ----------------
__global__ void detect_dtype_k(const void* __restrict__ inputs, int* __restrict__ dtflag)
{
    __shared__ int bad;
    int t = threadIdx.x;
    if (t == 0) bad = 0;
    __syncthreads();
    const u16* p = (const u16*)inputs;
    int l = 0;
    for (int i = t; i < 4096; i += 256){
        u16 v = p[i];
        int e = (v >> 7) & 0xFF;
        if (v != 0 && (e < 90 || e > 140)) l = 1;
    }
    if (l) atomicOr(&bad, 1);
    __syncthreads();
    if (t == 0) *dtflag = bad;   // 1 = fp32, 0 = bf16
}

// ---------------- mask detection -> maskflag[b][s] = 1.0 (pad) / 0.0 ----------------
__global__ void prep_mask_k(const void* __restrict__ mask, float* __restrict__ maskflag)
{
    __shared__ int bad32, bad16, bad8, evenNZ;
    int t = threadIdx.x;
    if (t == 0){ bad32 = 0; bad16 = 0; bad8 = 0; evenNZ = 0; }
    __syncthreads();
    const u32* w32 = (const u32*)mask;
    const u16* w16 = (const u16*)mask;
    const u8*  w8  = (const u8*)mask;
    int l32 = 0, l16 = 0, l8 = 0, lev = 0;
    for (int i = t; i < 2048; i += 256){ u32 v = w32[i]; l32 |= (v > 1u); }
    for (int i = t; i < 4096; i += 256){
        u16 v = w16[i];
        l16 |= (v != 0 && v != 0x3F80u);
        if ((i & 1) == 0 && v != 0) lev = 1;
    }
    for (int i = t; i < 8192; i += 256){ l8 |= (w8[i] > 1); }
    if (l32) atomicOr(&bad32, 1);
    if (l16) atomicOr(&bad16, 1);
    if (l8)  atomicOr(&bad8, 1);
    if (lev) atomicOr(&evenNZ, 1);
    __syncthreads();
    int mode;                       // 0=int32, 1=bf16, 2=uint8, 3=fp32
    if (!bad32)       mode = 0;
    else if (!bad16)  mode = evenNZ ? 1 : 3;
    else if (!bad8)   mode = 2;
    else              mode = 3;
    for (int i = t; i < kB * kS; i += 256){
        bool m;
        if (mode == 0)      m = (((const int*)mask)[i] != 0);
        else if (mode == 1) m = (w16[i] != 0);
        else if (mode == 2) m = (w8[i] != 0);
        else                m = (((const float*)mask)[i] != 0.f);
        maskflag[i] = m ? 1.f : 0.f;
    }
}

// ---------------- bias / fold-vector precompute ----------------
// bkq[o]  = sum_i bk[i]*Wq[i][o]        (bias of KQ = K@Wq, from bk inside K)
// bvo[o2] = sum_h bv[h]*Wo[o2][h]       (bv pushed through Wo; bo added in cv_k)
// ubq[e]  = sum_i bq[i]*Wk[i][e]        (enc-side part of bq.K)
// cbqbk   = bq.bk
__global__ void prep_bias_k(const void* __restrict__ Wq, const void* __restrict__ bq,
                            const void* __restrict__ Wk, const void* __restrict__ bk,
                            const void* __restrict__ bv, const void* __restrict__ Wo,
                            const void* __restrict__ bo,
                            const void* __restrict__ bih0, const void* __restrict__ bhh0,
                            const void* __restrict__ bih1, const void* __restrict__ bhh1,
                            float* __restrict__ bkq, float* __restrict__ bvo,
                            float* __restrict__ ubq, float* __restrict__ bof,
                            float* __restrict__ bias01, float* __restrict__ bias1,
                            float* __restrict__ cbqbk, const int* __restrict__ dtflag)
{
    int dt = *dtflag;
    int idx = blockIdx.x * 256 + threadIdx.x;
    if (idx < 1024){
        float s = 0.f;
        for (int i = 0; i < 1024; i++) s += ldin(bk, i, dt) * ldin(Wq, (size_t)i * 1024 + idx, dt);
        bkq[idx] = s;
    } else if (idx < 2048){ int o2 = idx - 1024;
        float s = 0.f;
        for (int h = 0; h < 1024; h++) s += ldin(bv, h, dt) * ldin(Wo, (size_t)o2 * 1024 + h, dt);
        bvo[o2] = s;
    } else if (idx < 3072){ int e = idx - 2048;
        float s = 0.f;
        for (int i = 0; i < 1024; i++) s += ldin(bq, i, dt) * ldin(Wk, (size_t)i * 1024 + e, dt);
        ubq[e] = s;
    } else if (idx < 4096){ int o2 = idx - 3072;
        bof[o2] = ldin(bo, o2, dt);
    } else if (idx < 8192){ int j = idx - 4096;
        bias01[j] = ldin(bih0, j, dt) + ldin(bhh0, j, dt);
    } else if (idx < 12288){ int j = idx - 8192;
        bias1[j] = ldin(bih1, j, dt) + ldin(bhh1, j, dt);
    } else if (idx == 12288){
        float s = 0.f;
        for (int i = 0; i < 1024; i++) s += ldin(bq, i, dt) * ldin(bk, i, dt);
        cbqbk[0] = s;
    }
}

// ---------------- inputs -> fp32 copy, same [B,T,E] layout ----------------
__global__ void copy_inputs_k(const void* __restrict__ inputs, float* __restrict__ xf,
                              const int* __restrict__ dtflag)
{
    int dt = *dtflag;
    int idx = blockIdx.x * 256 + threadIdx.x;   // grid 8192 -> 2097152
    xf[idx] = ldin(inputs, idx, dt);
}

// ---------------- initial states ----------------
__global__ void init_state_k(const void* __restrict__ enc_c, float* __restrict__ h0,
                             float* __restrict__ c0, float* __restrict__ h1,
                             float* __restrict__ c1, const int* __restrict__ dtflag)
{
    int dt = *dtflag;
    int idx = blockIdx.x * 256 + threadIdx.x;     // 32768
    int b = idx >> 10, h = idx & 1023;
    float cv = (h < 512) ? ldin(enc_c, (size_t)b * 512 + h, dt)
                         : ldin(enc_c, (size_t)(32 + b) * 512 + (h - 512), dt);
    h0[idx] = 0.f; h1[idx] = 0.f; c0[idx] = cv; c1[idx] = cv;
}

// ---------------- transpose to bf16: WT[e*ldt + j] = bf16(W[j*ldw + col_off + e]) ----------------
__global__ void transpose_b_k(const void* __restrict__ W, int ldw, int col_off,
                              u16* __restrict__ WT, int ldt, const int* __restrict__ dtflag)
{
    __shared__ float tile[64][65];
    int dt = *dtflag;
    int j0 = blockIdx.x * 64, e0 = blockIdx.y * 64;
    for (int i = 0; i < 16; i++){
        int idx = threadIdx.x + i * 256;
        int jr = idx >> 6, ec = idx & 63;
        tile[jr][ec] = ldin(W, (size_t)(j0 + jr) * ldw + col_off + e0 + ec, dt);
    }
    __syncthreads();
    for (int i = 0; i < 16; i++){
        int idx = threadIdx.x + i * 256;
        int er = idx >> 6, jc = idx & 63;
        WT[(size_t)(e0 + er) * ldt + j0 + jc] = f2b(tile[jc][er]);
    }
}

// ---------------- weight-weight fold GEMM: Out[e][c] = sum_k A[k][e] * B(k,c) ----------------
// BMODE 0: B addr k*1024+c (Wq) ; BMODE 1: B addr c*1024+k (Wo). K=1024, out fp32 1024x1024.
template<int BMODE>
__global__ __launch_bounds__(256) void gemm_ww_k(
    const void* __restrict__ A, const void* __restrict__ Bm,
    float* __restrict__ Out, const int* __restrict__ dtflag)
{
    __shared__ float As[32][68];
    __shared__ float Bs[32][68];
    const int dt = *dtflag;
    const int tid = threadIdx.x;
    const int tile_r = blockIdx.x * 64, tile_c = blockIdx.y * 64;
    const int r0 = (tid & 15) * 4, c0 = (tid >> 4) * 4;
    float acc[16];
    #pragma unroll
    for (int i = 0; i < 16; i++) acc[i] = 0.f;
    for (int k0 = 0; k0 < 1024; k0 += 32){
        int rr = tid & 63, kq = tid >> 6;
        #pragma unroll
        for (int i = 0; i < 8; i++){
            int k = kq * 8 + i;
            As[k][rr] = ldin(A, (size_t)(k0 + k) * 1024 + tile_r + rr, dt);
        }
        #pragma unroll
        for (int i = 0; i < 8; i++){
            int k = kq * 8 + i;
            size_t addr = (BMODE == 0) ? (size_t)(k0 + k) * 1024 + tile_c + rr
                                       : (size_t)(tile_c + rr) * 1024 + k0 + k;
            Bs[k][rr] = ldin(Bm, addr, dt);
        }
        __syncthreads();
        #pragma unroll
        for (int k = 0; k < 32; k++){
            float4 av = *(const float4*)&As[k][r0];
            float4 bv = *(const float4*)&Bs[k][c0];
            acc[0]  += av.x * bv.x; acc[1]  += av.x * bv.y; acc[2]  += av.x * bv.z; acc[3]  += av.x * bv.w;
            acc[4]  += av.y * bv.x; acc[5]  += av.y * bv.y; acc[6]  += av.y * bv.z; acc[7]  += av.y * bv.w;
            acc[8]  += av.z * bv.x; acc[9]  += av.z * bv.y; acc[10] += av.z * bv.z; acc[11] += av.z * bv.w;
            acc[12] += av.w * bv.x; acc[13] += av.w * bv.y; acc[14] += av.w * bv.z; acc[15] += av.w * bv.w;
        }
        __syncthreads();
    }
    #pragma unroll
    for (int i = 0; i < 4; i++){
        int gr = tile_r + r0 + i;
        #pragma unroll
        for (int jj = 0; jj < 4; jj++)
            Out[(size_t)gr * 1024 + tile_c + c0 + jj] = acc[i * 4 + jj];
    }
}

// ---------------- enc-side fold GEMM: bf16 out, row remap (s*32+b) -> [b][s] ----------------
// Outb[(b*256+s)*1024 + c] = bf16( (sum_e enc[(s*32+b)*1024+e]*Bw[e*1024+c] + bias[c]) * scale )
__global__ __launch_bounds__(256) void gemm_enc_k(
    const void* __restrict__ A, const float* __restrict__ Bw,
    u16* __restrict__ Outb, const float* __restrict__ bias, float scale,
    const int* __restrict__ dtflag)
{
    __shared__ float As[32][68];
    __shared__ float Bs[32][68];
    const int dt = *dtflag;
    const int tid = threadIdx.x;
    const int tile_r = blockIdx.x * 64, tile_c = blockIdx.y * 64;
    const int r0 = (tid & 15) * 4, c0 = (tid >> 4) * 4;
    float acc[16];
    #pragma unroll
    for (int i = 0; i < 16; i++) acc[i] = 0.f;
    for (int k0 = 0; k0 < 1024; k0 += 32){
        int rr = tid & 63, kq = tid >> 6;
        size_t base = (size_t)(tile_r + rr) * 1024 + k0 + kq * 8;
        #pragma unroll
        for (int i = 0; i < 8; i++) As[kq * 8 + i][rr] = ldin(A, base + i, dt);
        #pragma unroll
        for (int i = 0; i < 8; i++){
            int k = kq * 8 + i;
            Bs[k][rr] = Bw[(size_t)(k0 + k) * 1024 + tile_c + rr];
        }
        __syncthreads();
        #pragma unroll
        for (int k = 0; k < 32; k++){
            float4 av = *(const float4*)&As[k][r0];
            float4 bv = *(const float4*)&Bs[k][c0];
            acc[0]  += av.x * bv.x; acc[1]  += av.x * bv.y; acc[2]  += av.x * bv.z; acc[3]  += av.x * bv.w;
            acc[4]  += av.y * bv.x; acc[5]  += av.y * bv.y; acc[6]  += av.y * bv.z; acc[7]  += av.y * bv.w;
            acc[8]  += av.z * bv.x; acc[9]  += av.z * bv.y; acc[10] += av.z * bv.z; acc[11] += av.z * bv.w;
            acc[12] += av.w * bv.x; acc[13] += av.w * bv.y; acc[14] += av.w * bv.z; acc[15] += av.w * bv.w;
        }
        __syncthreads();
    }
    #pragma unroll
    for (int i = 0; i < 4; i++){
        int gr = tile_r + r0 + i;
        int b = gr & 31, s = gr >> 5;
        #pragma unroll
        for (int jj = 0; jj < 4; jj++){
            int gc = tile_c + c0 + jj;
            Outb[(((size_t)((b << 8) | s)) << 10) + gc] = f2b((acc[i * 4 + jj] + bias[gc]) * scale);
        }
    }
}

// ---------------- skbqs[b][s] = (bq.K[s,b,:]) * scale = (sum_e ubq[e]*enc + bq.bk)/32 ----------------
__global__ __launch_bounds__(256) void skbq_k(
    const void* __restrict__ enc, const float* __restrict__ ubq,
    const float* __restrict__ cbqbk, float* __restrict__ skbqs,
    const int* __restrict__ dtflag)
{
    int dt = *dtflag;
    int w = (blockIdx.x * 256 + threadIdx.x) >> 6;   // 0..8191 = s*32+b
    int lane = threadIdx.x & 63;
    int s = w >> 5, b = w & 31;
    size_t base = (size_t)w * 1024 + lane * 16;
    float acc = 0.f;
    #pragma unroll
    for (int i = 0; i < 16; i++) acc += ubq[lane * 16 + i] * ldin(enc, base + i, dt);
    #pragma unroll
    for (int off = 32; off; off >>= 1) acc += __shfl_down(acc, off, 64);
    if (lane == 0) skbqs[b * 256 + s] = (acc + cbqbk[0]) * 0.03125f;
}

// ---------------- per-step: scores[b][s] = mask ? -1e9 : c1.KQb[b,s,:] + skbqs ----------------
__global__ __launch_bounds__(256) void scores_k(
    const float* __restrict__ c1f, const u16* __restrict__ KQb,
    const float* __restrict__ skbqs, const float* __restrict__ maskflag,
    float* __restrict__ scores)
{
    int w = (blockIdx.x * 256 + threadIdx.x) >> 6;    // 0..8191
    int lane = threadIdx.x & 63;
    int b = w >> 8, s = w & 255;
    const u16*  kr = KQb + (((size_t)((b << 8) | s)) << 10) + lane * 16;
    const float* cr = c1f + ((size_t)b << 10) + lane * 16;
    float cb[16];
    *(float4*)&cb[0]  = *(const float4*)(cr);
    *(float4*)&cb[4]  = *(const float4*)(cr + 4);
    *(float4*)&cb[8]  = *(const float4*)(cr + 8);
    *(float4*)&cb[12] = *(const float4*)(cr + 12);
    u32 kb[8];
    *(uint4*)&kb[0] = *(const uint4*)(kr);
    *(uint4*)&kb[4] = *(const uint4*)(kr + 8);
    float acc = 0.f;
    #pragma unroll
    for (int i = 0; i < 8; i++){
        acc += cb[2 * i]     * b2f((u16)(kb[i] & 0xFFFFu));
        acc += cb[2 * i + 1] * b2f((u16)(kb[i] >> 16));
    }
    #pragma unroll
    for (int off = 32; off; off >>= 1) acc += __shfl_down(acc, off, 64);
    if (lane == 0){
        int idx = b * 256 + s;
        scores[idx] = (maskflag[idx] != 0.f) ? -1e9f : acc + skbqs[idx];
    }
}

// ---------------- per-step: softmax (redundant/block) + ctx = attn@Vob + bo ----------------
// grid 512 = (b<<4 | ht), ht covers 64 h each
__global__ __launch_bounds__(256) void cv_k(
    const float* __restrict__ scores, const u16* __restrict__ Vob,
    const float* __restrict__ bof, float* __restrict__ ctx)
{
    __shared__ float attn[256];
    __shared__ float wred[8];
    __shared__ float part[4][64];
    int b = blockIdx.x >> 4, ht = blockIdx.x & 15;
    int tid = threadIdx.x;
    float scv = scores[b * 256 + tid];
    float m = scv;
    #pragma unroll
    for (int off = 32; off; off >>= 1) m = fmaxf(m, __shfl_down(m, off, 64));
    if ((tid & 63) == 0) wred[tid >> 6] = m;
    __syncthreads();
    float mm = fmaxf(fmaxf(wred[0], wred[1]), fmaxf(wred[2], wred[3]));
    float ex = expf(scv - mm);
    float ssum = ex;
    #pragma unroll
    for (int off = 32; off; off >>= 1) ssum += __shfl_down(ssum, off, 64);
    if ((tid & 63) == 0) wred[4 + (tid >> 6)] = ssum;
    __syncthreads();
    float tot = (wred[4] + wred[5]) + (wred[6] + wred[7]);
    attn[tid] = ex / tot;
    __syncthreads();
    int hl = tid & 63, scn = tid >> 6;
    int h = ht * 64 + hl;
    const u16* vcol = Vob + ((size_t)b << 18) + h;
    float acc = 0.f;
    #pragma unroll 8
    for (int s = scn; s < 256; s += 4) acc += attn[s] * b2f(vcol[(size_t)s << 10]);
    part[scn][hl] = acc;
    __syncthreads();
    if (tid < 64){
        float v = (part[0][tid] + part[1][tid]) + (part[2][tid] + part[3][tid]);
        ctx[(b << 10) + ht * 64 + tid] = v + bof[ht * 64 + tid];
    }
}

// ---------------- layer-0 gates split-K (bf16 weights): x_t, ctx, h0 ----------------
// grid (16 jt, 20 es): es<4 -> x (k=512), es<12 -> ctx, else h0
__global__ __launch_bounds__(256) void gates0_k(
    const u16* __restrict__ WTx, const u16* __restrict__ WTc, const u16* __restrict__ WTh,
    const float* __restrict__ xt, const float* __restrict__ ctx, const float* __restrict__ h0,
    float* __restrict__ partial)
{
    int jt = blockIdx.x, es = blockIdx.y;
    int j = jt * 256 + threadIdx.x;
    const u16* WT; const float* act; int e0, bstride;
    if (es < 4)       { WT = WTx; act = xt;  e0 = es * 128;        bstride = kT * kE; }
    else if (es < 12) { WT = WTc; act = ctx; e0 = (es - 4) * 128;  bstride = 1024; }
    else              { WT = WTh; act = h0;  e0 = (es - 12) * 128; bstride = 1024; }
    float acc[32];
    #pragma unroll
    for (int b = 0; b < 32; b++) acc[b] = 0.f;
    #pragma unroll
    for (int ec = 0; ec < 2; ec++){
        float w[64];
        const u16* wp = WT + (size_t)(e0 + ec * 64) * kG + j;
        #pragma unroll
        for (int k = 0; k < 64; k++) w[k] = b2f(wp[(size_t)k * kG]);
        const float* ap = act + e0 + ec * 64;
        #pragma unroll 4
        for (int b = 0; b < 32; b++){
            const float* ab = ap + (size_t)b * bstride;
            float s0 = 0.f, s1 = 0.f;
            #pragma unroll
            for (int k = 0; k < 64; k += 2){ s0 += w[k] * ab[k]; s1 += w[k + 1] * ab[k + 1]; }
            acc[b] += s0 + s1;
        }
    }
    float* po = partial + (size_t)(es * 32) * kG + j;
    #pragma unroll 4
    for (int b = 0; b < 32; b++) po[(size_t)b * kG] = acc[b];
}

// ---------------- layer-1 gates split-K (bf16 weights): h0(new), h1 ----------------
// grid (16 jt, 16 es): es<8 -> h0 via WTa, else h1 via WTb
__global__ __launch_bounds__(256) void gates1_k(
    const u16* __restrict__ WTa, const u16* __restrict__ WTb,
    const float* __restrict__ h0, const float* __restrict__ h1,
    float* __restrict__ partial)
{
    int jt = blockIdx.x, es = blockIdx.y;
    int j = jt * 256 + threadIdx.x;
    const u16* WT   = (es < 8) ? WTa : WTb;
    const float* act = (es < 8) ? h0  : h1;
    int e0 = (es & 7) * 128;
    float acc[32];
    #pragma unroll
    for (int b = 0; b < 32; b++) acc[b] = 0.f;
    #pragma unroll
    for (int ec = 0; ec < 2; ec++){
        float w[64];
        const u16* wp = WT + (size_t)(e0 + ec * 64) * kG + j;
        #pragma unroll
        for (int k = 0; k < 64; k++) w[k] = b2f(wp[(size_t)k * kG]);
        const float* ap = act + e0 + ec * 64;
        #pragma unroll 4
        for (int b = 0; b < 32; b++){
            const float* ab = ap + (b << 10);
            float s0 = 0.f, s1 = 0.f;
            #pragma unroll
            for (int k = 0; k < 64; k += 2){ s0 += w[k] * ab[k]; s1 += w[k + 1] * ab[k + 1]; }
            acc[b] += s0 + s1;
        }
    }
    float* po = partial + (size_t)(es * 32) * kG + j;
    #pragma unroll 4
    for (int b = 0; b < 32; b++) po[(size_t)b * kG] = acc[b];
}

// ---------------- LSTM cell: g = sum partials + bias; update c,h; optional fp32 y ----------------
__global__ __launch_bounds__(256) void cell_k(
    const float* __restrict__ partial, int nsl, const float* __restrict__ biasv,
    const float* __restrict__ c_prev, float* __restrict__ c_out, float* __restrict__ h_out,
    float* __restrict__ y_out, int t)
{
    int idx = blockIdx.x * 256 + threadIdx.x;     // 32768
    int b = idx >> 10, h = idx & 1023;
    float g[4];
    #pragma unroll
    for (int gi = 0; gi < 4; gi++){
        int j = gi * 1024 + h;
        float s = biasv[j];
        for (int es = 0; es < nsl; es++) s += partial[(size_t)(es * 32 + b) * kG + j];
        g[gi] = s;
    }
    float gi_ = sigf(g[0]);
    float gf_ = sigf(g[1]);
    float gg_ = tanhf(g[2]);
    float go_ = sigf(g[3]);
    float c = gf_ * c_prev[idx] + gi_ * gg_;
    float hh = go_ * tanhf(c);
    c_out[idx] = c;
    h_out[idx] = hh;
    if (y_out) y_out[((size_t)b * kT + t) * kH + h] = hh;
}

extern "C" void kernel_launch(void* const* d_in, const int* in_sizes, int n_in,
                              void* d_out, int out_size, void* d_ws, size_t ws_size,
                              hipStream_t stream)
{
    const void* inputs = d_in[0];
    const void* enc    = d_in[1];
    const void* enc_c  = d_in[2];
    const void* mask   = d_in[3];
    const void* Wq   = d_in[4];
    const void* bq   = d_in[5];
    const void* Wk   = d_in[6];
    const void* bk   = d_in[7];
    const void* Wv   = d_in[8];
    const void* bv   = d_in[9];
    const void* Wo   = d_in[10];
    const void* bo   = d_in[11];
    const void* Wih0 = d_in[12];
    const void* Whh0 = d_in[13];
    const void* bih0 = d_in[14];
    const void* bhh0 = d_in[15];
    const void* Wih1 = d_in[16];
    const void* Whh1 = d_in[17];
    const void* bih1 = d_in[18];
    const void* bhh1 = d_in[19];
    float* out = (float*)d_out;
    (void)in_sizes; (void)n_in; (void)out_size; (void)ws_size;

    char* ws = (char*)d_ws;
    size_t off = 0;
    auto alloc = [&](size_t bytes) -> void* {
        void* p = ws + off; off += (bytes + 255) & ~(size_t)255; return p;
    };
    // union: Wkq+Wvo fp32 (precompute, 8MB) alias partial (loop, 10.5MB)
    float* uni    = (float*)alloc((size_t)20 * 32 * kG * 4);
    float* Wkq    = uni;
    float* Wvo    = uni + (size_t)1024 * 1024;
    float* partial= uni;
    u16*  KQb   = (u16*)alloc((size_t)kB * kS * kH * 2);    // [b][s][o]  16.8MB (scale 1/32 folded)
    u16*  Vob   = (u16*)alloc((size_t)kB * kS * kH * 2);    // [b][s][o2] 16.8MB (incl. bvo)
    u16*  WTxb  = (u16*)alloc((size_t)kE * kG * 2);         // Wih0[:,1024:]^T  4.2MB
    u16*  WTcb  = (u16*)alloc((size_t)kH * kG * 2);         // Wih0[:,0:1024]^T 8.4MB
    u16*  WThh0b= (u16*)alloc((size_t)kH * kG * 2);
    u16*  WTih1b= (u16*)alloc((size_t)kH * kG * 2);
    u16*  WThh1b= (u16*)alloc((size_t)kH * kG * 2);
    float* xf    = (float*)alloc((size_t)kB * kT * kE * 4); // 8.4MB [b][t][e]
    float* bkq   = (float*)alloc(1024 * 4);
    float* bvo   = (float*)alloc(1024 * 4);
    float* ubq   = (float*)alloc(1024 * 4);
    float* bof   = (float*)alloc(1024 * 4);
    float* bias01= (float*)alloc(4096 * 4);
    float* bias1 = (float*)alloc(4096 * 4);
    float* cbqbk = (float*)alloc(256);
    float* skbqs = (float*)alloc(kB * kS * 4);
    float* maskflag = (float*)alloc(kB * kS * 4);
    float* scores= (float*)alloc(kB * kS * 4);
    float* ctx   = (float*)alloc(kB * kH * 4);
    float* h0f   = (float*)alloc(kB * kH * 4);
    float* c0f   = (float*)alloc(kB * kH * 4);
    float* h1f   = (float*)alloc(kB * kH * 4);
    float* c1f   = (float*)alloc(kB * kH * 4);
    int*   dtflag= (int*)alloc(256);

    // ---- one-time precompute ----
    detect_dtype_k<<<1, 256, 0, stream>>>(inputs, dtflag);
    prep_mask_k<<<1, 256, 0, stream>>>(mask, maskflag);
    prep_bias_k<<<49, 256, 0, stream>>>(Wq, bq, Wk, bk, bv, Wo, bo,
                                        bih0, bhh0, bih1, bhh1,
                                        bkq, bvo, ubq, bof, bias01, bias1, cbqbk, dtflag);
    copy_inputs_k<<<8192, 256, 0, stream>>>(inputs, xf, dtflag);
    init_state_k<<<128, 256, 0, stream>>>(enc_c, h0f, c0f, h1f, c1f, dtflag);
    transpose_b_k<<<dim3(64, 8),  256, 0, stream>>>(Wih0, 1536, 1024, WTxb,   4096, dtflag);
    transpose_b_k<<<dim3(64, 16), 256, 0, stream>>>(Wih0, 1536, 0,    WTcb,   4096, dtflag);
    transpose_b_k<<<dim3(64, 16), 256, 0, stream>>>(Whh0, 1024, 0,    WThh0b, 4096, dtflag);
    transpose_b_k<<<dim3(64, 16), 256, 0, stream>>>(Wih1, 1024, 0,    WTih1b, 4096, dtflag);
    transpose_b_k<<<dim3(64, 16), 256, 0, stream>>>(Whh1, 1024, 0,    WThh1b, 4096, dtflag);
    // Wkq[e][o] = sum_i Wk[i][e]*Wq[i][o] ; Wvo[e][o2] = sum_h Wv[h][e]*Wo[o2][h]
    gemm_ww_k<0><<<dim3(16, 16), 256, 0, stream>>>(Wk, Wq, Wkq, dtflag);
    gemm_ww_k<1><<<dim3(16, 16), 256, 0, stream>>>(Wv, Wo, Wvo, dtflag);
    // KQb = (enc@Wkq + bkq)/32 ; Vob = enc@Wvo + bvo   (bf16, [b][s][.])
    gemm_enc_k<<<dim3(128, 16), 256, 0, stream>>>(enc, Wkq, KQb, bkq, 0.03125f, dtflag);
    gemm_enc_k<<<dim3(128, 16), 256, 0, stream>>>(enc, Wvo, Vob, bvo, 1.0f, dtflag);
    skbq_k<<<2048, 256, 0, stream>>>(enc, ubq, cbqbk, skbqs, dtflag);

    // ---- recurrent loop: 6 kernels/step ----
    for (int t = 0; t < kT; t++){
        scores_k<<<2048, 256, 0, stream>>>(c1f, KQb, skbqs, maskflag, scores);
        cv_k<<<512, 256, 0, stream>>>(scores, Vob, bof, ctx);
        gates0_k<<<dim3(16, 20), 256, 0, stream>>>(WTxb, WTcb, WThh0b,
                                                   xf + (size_t)t * kE, ctx, h0f, partial);
        cell_k<<<128, 256, 0, stream>>>(partial, 20, bias01, c0f, c0f, h0f, nullptr, t);
        gates1_k<<<dim3(16, 16), 256, 0, stream>>>(WTih1b, WThh1b, h0f, h1f, partial);
        cell_k<<<128, 256, 0, stream>>>(partial, 16, bias1, c1f, c1f, h1f, out, t);
    }
}